// Round 1
// baseline (145.197 us; speedup 1.0000x reference)
//
#include <hip/hip_runtime.h>
#include <hip/hip_bf16.h>

#define NROWS 4096
#define DMODEL 512
#define NHEAD 8
#define DKH 64
#define ND (NROWS * DMODEL)   // 2097152
#define DD (DMODEL * DMODEL)  // 262144

typedef unsigned short u16;
typedef __attribute__((ext_vector_type(8))) short short8;
typedef __attribute__((ext_vector_type(4))) float floatx4;

// ---------- helpers ----------
__device__ __forceinline__ u16 f2b(float f) {
    unsigned u = __float_as_uint(f);
    unsigned r = (u + 0x7fffu + ((u >> 16) & 1u)) >> 16;
    return (u16)r;
}
__device__ __forceinline__ float b2f(u16 v) {
    return __uint_as_float(((unsigned)v) << 16);
}
__device__ __forceinline__ void async16(const void* g, void* l) {
    // global -> LDS direct, 16B per lane; LDS dest = wave-uniform base + lane*16
    __builtin_amdgcn_global_load_lds(g, l, 16, 0, 0);
}

// ---------- 1. fp32 -> bf16 convert (x_q, x_k, x_v) ----------
__global__ __launch_bounds__(256) void convert_x(
    const float* __restrict__ s0, const float* __restrict__ s1,
    const float* __restrict__ s2, u16* __restrict__ d0, u16* __restrict__ d1,
    u16* __restrict__ d2, int nElem) {
    const float* s = blockIdx.z == 0 ? s0 : (blockIdx.z == 1 ? s1 : s2);
    u16* d = blockIdx.z == 0 ? d0 : (blockIdx.z == 1 ? d1 : d2);
    int i = (blockIdx.x * blockDim.x + threadIdx.x) * 4;
    if (i < nElem) {
        float4 v = *(const float4*)(s + i);
        ushort4 o;
        o.x = f2b(v.x); o.y = f2b(v.y); o.z = f2b(v.z); o.w = f2b(v.w);
        *(ushort4*)(d + i) = o;
    }
}

// ---------- 2. W (K x N) -> Wt (N x K) bf16 ----------
__global__ __launch_bounds__(256) void convert_w(
    const float* __restrict__ W0, const float* __restrict__ W1,
    const float* __restrict__ W2, const float* __restrict__ W3,
    u16* __restrict__ T0, u16* __restrict__ T1, u16* __restrict__ T2,
    u16* __restrict__ T3) {
    __shared__ float tile[32][33];
    int z = blockIdx.z;
    const float* W = z == 0 ? W0 : (z == 1 ? W1 : (z == 2 ? W2 : W3));
    u16* T = z == 0 ? T0 : (z == 1 ? T1 : (z == 2 ? T2 : T3));
    int n0 = blockIdx.x * 32, k0 = blockIdx.y * 32;
    int tx = threadIdx.x, ty = threadIdx.y;  // (32, 8)
#pragma unroll
    for (int r = 0; r < 32; r += 8)
        tile[ty + r][tx] = W[(size_t)(k0 + ty + r) * DMODEL + n0 + tx];
    __syncthreads();
#pragma unroll
    for (int r = 0; r < 32; r += 8) {
        int n = n0 + ty + r, k = k0 + tx;
        T[(size_t)n * DMODEL + k] = f2b(tile[tx][ty + r]);
    }
}

// ---------- 3/5. bf16 MFMA GEMM: C[M,N] = A[M,K] @ Wt[N,K]^T + bias ----------
// M=4096 (per z), N=512, K=512. Tile 128x64, BK=32, 256 thr (4 waves, 2x2).
template <int OUTF>
__device__ __forceinline__ void gemm_bt_body(const u16* __restrict__ A,
                                             const u16* __restrict__ Bt,
                                             const float* __restrict__ bias,
                                             void* __restrict__ Cout) {
    __shared__ __align__(16) u16 lA[128 * 32];
    __shared__ __align__(16) u16 lB[64 * 32];
    const int tid = threadIdx.x;
    const int wave = tid >> 6, lane = tid & 63;
    const int tileM = blockIdx.y * 128;
    const int tileN = blockIdx.x * 64;
    const int wm = wave >> 1, wn = wave & 1;

    floatx4 acc[4][2];
#pragma unroll
    for (int i = 0; i < 4; i++)
#pragma unroll
        for (int j = 0; j < 2; j++) acc[i][j] = (floatx4){0.f, 0.f, 0.f, 0.f};

    const int lr4 = lane >> 2;   // 0..15 : row within 16-row chunk (staging)
    const int ls = lane & 3;     // 16B slot within row (staging)
    const int lrow = lane & 15;  // fragment row/col
    const int sk = lane >> 4;    // fragment k-slot (8 bf16 each)

    for (int t = 0; t < 16; ++t) {
        const int k0 = t * 32;
        // stage A: 8 chunks of 16 rows (1KB each), 2 per wave
#pragma unroll
        for (int i = 0; i < 2; i++) {
            int c = wave * 2 + i;
            int r = c * 16 + lr4;
            int s = ls ^ ((r >> 1) & 3);  // pre-swizzle global source slot
            async16(A + (size_t)(tileM + r) * 512 + k0 + s * 8, &lA[c * 512]);
        }
        // stage B: 4 chunks, 1 per wave
        {
            int r = wave * 16 + lr4;
            int s = ls ^ ((r >> 1) & 3);
            async16(Bt + (size_t)(tileN + r) * 512 + k0 + s * 8, &lB[wave * 512]);
        }
        __syncthreads();

        short8 bfr[2];
#pragma unroll
        for (int ni = 0; ni < 2; ++ni) {
            int r = wn * 32 + ni * 16 + lrow;
            int s = sk ^ ((r >> 1) & 3);  // matching read swizzle
            bfr[ni] = *(const short8*)&lB[r * 32 + s * 8];
        }
#pragma unroll
        for (int mi = 0; mi < 4; ++mi) {
            int r = wm * 64 + mi * 16 + lrow;
            int s = sk ^ ((r >> 1) & 3);
            short8 af = *(const short8*)&lA[r * 32 + s * 8];
#pragma unroll
            for (int ni = 0; ni < 2; ++ni)
                acc[mi][ni] = __builtin_amdgcn_mfma_f32_16x16x32_bf16(
                    af, bfr[ni], acc[mi][ni], 0, 0, 0);
        }
        __syncthreads();
    }

    // epilogue: C/D layout col = lane&15, row = (lane>>4)*4 + reg
#pragma unroll
    for (int mi = 0; mi < 4; ++mi) {
#pragma unroll
        for (int ni = 0; ni < 2; ++ni) {
            int col = tileN + wn * 32 + ni * 16 + lrow;
            float bv = bias[col];
#pragma unroll
            for (int r2 = 0; r2 < 4; r2++) {
                int row = tileM + wm * 64 + mi * 16 + sk * 4 + r2;
                float val = acc[mi][ni][r2] + bv;
                if (OUTF)
                    ((float*)Cout)[(size_t)row * 512 + col] = val;
                else
                    ((u16*)Cout)[(size_t)row * 512 + col] = f2b(val);
            }
        }
    }
}

__global__ __launch_bounds__(256) void proj3(
    const u16* __restrict__ xq, const u16* __restrict__ xk,
    const u16* __restrict__ xv, const u16* __restrict__ wtq,
    const u16* __restrict__ wtk, const u16* __restrict__ wtv,
    const float* __restrict__ bq, const float* __restrict__ bk,
    const float* __restrict__ bv, u16* __restrict__ Q, u16* __restrict__ K,
    u16* __restrict__ V) {
    int z = blockIdx.z;
    const u16* A = z == 0 ? xq : (z == 1 ? xk : xv);
    const u16* Bt = z == 0 ? wtq : (z == 1 ? wtk : wtv);
    const float* bias = z == 0 ? bq : (z == 1 ? bk : bv);
    u16* C = z == 0 ? Q : (z == 1 ? K : V);
    gemm_bt_body<0>(A, Bt, bias, C);
}

__global__ __launch_bounds__(256) void out_gemm(const u16* __restrict__ T,
                                                const u16* __restrict__ wto,
                                                const float* __restrict__ bo,
                                                float* __restrict__ C) {
    gemm_bt_body<1>(T, wto, bo, C);
}

// ---------- 4. rank-1 channel attention + residual-diff ----------
// per (n,h): x_att[i] = sum_j exp(q_i*k_j/8) v_j / sum_j exp(q_i*k_j/8)
__global__ __launch_bounds__(256) void attn_kernel(
    const u16* __restrict__ Qb, const u16* __restrict__ Kb,
    const u16* __restrict__ Vb, const float* __restrict__ xq,
    u16* __restrict__ Tout) {
    __shared__ float lk[4][64];
    __shared__ float lv[4][64];
    const int wave = threadIdx.x >> 6, lane = threadIdx.x & 63;
    const int p = blockIdx.x * 4 + wave;  // (n,h) pair, < 32768
    const int n = p >> 3, h = p & 7;
    const size_t base = (size_t)n * DMODEL + h * DKH;

    float q = b2f(Qb[base + lane]);
    lk[wave][lane] = b2f(Kb[base + lane]) * 0.125f;  // 1/sqrt(64)
    lv[wave][lane] = b2f(Vb[base + lane]);
    __syncthreads();

    float num = 0.f, den = 0.f;
#pragma unroll
    for (int j = 0; j < 64; j += 4) {
        float4 kv = *(const float4*)&lk[wave][j];
        float4 vv = *(const float4*)&lv[wave][j];
        float e0 = __expf(q * kv.x);
        float e1 = __expf(q * kv.y);
        float e2 = __expf(q * kv.z);
        float e3 = __expf(q * kv.w);
        den += e0 + e1 + e2 + e3;
        num += e0 * vv.x + e1 * vv.y + e2 * vv.z + e3 * vv.w;
    }
    float t = xq[base + lane] - num / den;
    Tout[base + lane] = f2b(t);
}

// ---------- launch ----------
extern "C" void kernel_launch(void* const* d_in, const int* in_sizes, int n_in,
                              void* d_out, int out_size, void* d_ws,
                              size_t ws_size, hipStream_t stream) {
    const float* x_q = (const float*)d_in[0];
    const float* x_k = (const float*)d_in[1];
    const float* x_v = (const float*)d_in[2];
    const float* Wq = (const float*)d_in[3];
    const float* bq = (const float*)d_in[4];
    const float* Wk = (const float*)d_in[5];
    const float* bk = (const float*)d_in[6];
    const float* Wv = (const float*)d_in[7];
    const float* bv = (const float*)d_in[8];
    const float* Wo = (const float*)d_in[9];
    const float* bo = (const float*)d_in[10];

    u16* ws = (u16*)d_ws;
    u16* xqb = ws;
    u16* xkb = xqb + ND;
    u16* xvb = xkb + ND;
    u16* wtq = xvb + ND;
    u16* wtk = wtq + DD;
    u16* wtv = wtk + DD;
    u16* wto = wtv + DD;
    u16* Qb = wto + DD;
    u16* Kb = Qb + ND;
    u16* Vb = Kb + ND;
    u16* Tb = Vb + ND;

    convert_x<<<dim3(ND / 4 / 256, 1, 3), 256, 0, stream>>>(x_q, x_k, x_v, xqb,
                                                            xkb, xvb, ND);
    convert_w<<<dim3(16, 16, 4), dim3(32, 8), 0, stream>>>(Wq, Wk, Wv, Wo, wtq,
                                                           wtk, wtv, wto);
    proj3<<<dim3(DMODEL / 64, NROWS / 128, 3), 256, 0, stream>>>(
        xqb, xkb, xvb, wtq, wtk, wtv, bq, bk, bv, Qb, Kb, Vb);
    attn_kernel<<<dim3(NROWS * NHEAD / 4), 256, 0, stream>>>(Qb, Kb, Vb, x_q,
                                                             Tb);
    out_gemm<<<dim3(DMODEL / 64, NROWS / 128), 256, 0, stream>>>(
        Tb, wto, bo, (float*)d_out);
}

// Round 2
// 143.590 us; speedup vs baseline: 1.0112x; 1.0112x over previous
//
#include <hip/hip_runtime.h>
#include <hip/hip_bf16.h>

#define NROWS 4096
#define DMODEL 512
#define NHEAD 8
#define DKH 64
#define ND (NROWS * DMODEL)   // 2097152
#define DD (DMODEL * DMODEL)  // 262144

typedef unsigned short u16;
typedef __attribute__((ext_vector_type(8))) short short8;
typedef __attribute__((ext_vector_type(4))) float floatx4;

// ---------- helpers ----------
__device__ __forceinline__ u16 f2b(float f) {
    unsigned u = __float_as_uint(f);
    unsigned r = (u + 0x7fffu + ((u >> 16) & 1u)) >> 16;
    return (u16)r;
}
__device__ __forceinline__ float b2f(u16 v) {
    return __uint_as_float(((unsigned)v) << 16);
}
__device__ __forceinline__ void async16(const void* g, void* l) {
    // global -> LDS direct, 16B per lane; LDS dest = wave-uniform base + lane*16
    __builtin_amdgcn_global_load_lds(g, l, 16, 0, 0);
}

// ---------- 1. fp32 -> bf16 convert (x_q, x_k, x_v) ----------
__global__ __launch_bounds__(256) void convert_x(
    const float* __restrict__ s0, const float* __restrict__ s1,
    const float* __restrict__ s2, u16* __restrict__ d0, u16* __restrict__ d1,
    u16* __restrict__ d2, int nElem) {
    const float* s = blockIdx.z == 0 ? s0 : (blockIdx.z == 1 ? s1 : s2);
    u16* d = blockIdx.z == 0 ? d0 : (blockIdx.z == 1 ? d1 : d2);
    int i = (blockIdx.x * blockDim.x + threadIdx.x) * 4;
    if (i < nElem) {
        float4 v = *(const float4*)(s + i);
        ushort4 o;
        o.x = f2b(v.x); o.y = f2b(v.y); o.z = f2b(v.z); o.w = f2b(v.w);
        *(ushort4*)(d + i) = o;
    }
}

// ---------- 2. W (K x N) -> Wt (N x K) bf16 ----------
__global__ __launch_bounds__(256) void convert_w(
    const float* __restrict__ W0, const float* __restrict__ W1,
    const float* __restrict__ W2, const float* __restrict__ W3,
    u16* __restrict__ T0, u16* __restrict__ T1, u16* __restrict__ T2,
    u16* __restrict__ T3) {
    __shared__ float tile[32][33];
    int z = blockIdx.z;
    const float* W = z == 0 ? W0 : (z == 1 ? W1 : (z == 2 ? W2 : W3));
    u16* T = z == 0 ? T0 : (z == 1 ? T1 : (z == 2 ? T2 : T3));
    int n0 = blockIdx.x * 32, k0 = blockIdx.y * 32;
    int tx = threadIdx.x, ty = threadIdx.y;  // (32, 8)
#pragma unroll
    for (int r = 0; r < 32; r += 8)
        tile[ty + r][tx] = W[(size_t)(k0 + ty + r) * DMODEL + n0 + tx];
    __syncthreads();
#pragma unroll
    for (int r = 0; r < 32; r += 8) {
        int n = n0 + ty + r, k = k0 + tx;
        T[(size_t)n * DMODEL + k] = f2b(tile[tx][ty + r]);
    }
}

// ---------- 3/5. bf16 MFMA GEMM (m97 structure): C = A[M,K] @ Wt[N,K]^T + b
// Tile 128x128, BK=32, 256 thr = 4 waves (2x2), per-wave 64x64, acc[4][4].
// Per K-step/wave: 4 global_load_lds(16B), 8 ds_read_b128, 16 MFMA.
template <int OUTF>
__device__ __forceinline__ void gemm128_body(const u16* __restrict__ A,
                                             const u16* __restrict__ Bt,
                                             const float* __restrict__ bias,
                                             void* __restrict__ Cout) {
    __shared__ __align__(16) u16 lA[128 * 32];
    __shared__ __align__(16) u16 lB[128 * 32];
    const int tid = threadIdx.x;
    const int wave = tid >> 6, lane = tid & 63;
    const int tileM = blockIdx.y * 128;
    const int tileN = blockIdx.x * 128;
    const int wm = wave >> 1, wn = wave & 1;

    floatx4 acc[4][4];
#pragma unroll
    for (int i = 0; i < 4; i++)
#pragma unroll
        for (int j = 0; j < 4; j++) acc[i][j] = (floatx4){0.f, 0.f, 0.f, 0.f};

    const int lr4 = lane >> 2;   // 0..15 : row within 16-row staging chunk
    const int ls = lane & 3;     // 16B slot within row (staging)
    const int lrow = lane & 15;  // fragment row/col
    const int sk = lane >> 4;    // fragment k-slot (8 bf16 each)

    for (int t = 0; t < 16; ++t) {
        const int k0 = t * 32;
        // stage A+B: 8 chunks of 16 rows each (1KB per async16); 2 per wave each
#pragma unroll
        for (int i = 0; i < 2; i++) {
            int c = wave * 2 + i;
            int r = c * 16 + lr4;
            int s = ls ^ ((r >> 1) & 3);  // pre-swizzle global source slot
            async16(A + (size_t)(tileM + r) * 512 + k0 + s * 8, &lA[c * 512]);
            async16(Bt + (size_t)(tileN + r) * 512 + k0 + s * 8, &lB[c * 512]);
        }
        __syncthreads();

        short8 afr[4], bfr[4];
#pragma unroll
        for (int ni = 0; ni < 4; ++ni) {
            int r = wn * 64 + ni * 16 + lrow;
            int s = sk ^ ((r >> 1) & 3);  // matching read swizzle
            bfr[ni] = *(const short8*)&lB[r * 32 + s * 8];
        }
#pragma unroll
        for (int mi = 0; mi < 4; ++mi) {
            int r = wm * 64 + mi * 16 + lrow;
            int s = sk ^ ((r >> 1) & 3);
            afr[mi] = *(const short8*)&lA[r * 32 + s * 8];
        }
#pragma unroll
        for (int mi = 0; mi < 4; ++mi)
#pragma unroll
            for (int ni = 0; ni < 4; ++ni)
                acc[mi][ni] = __builtin_amdgcn_mfma_f32_16x16x32_bf16(
                    afr[mi], bfr[ni], acc[mi][ni], 0, 0, 0);
        __syncthreads();
    }

    // epilogue: C/D layout col = lane&15, row = (lane>>4)*4 + reg
#pragma unroll
    for (int mi = 0; mi < 4; ++mi) {
#pragma unroll
        for (int ni = 0; ni < 4; ++ni) {
            int col = tileN + wn * 64 + ni * 16 + lrow;
            float bv = bias[col];
#pragma unroll
            for (int r2 = 0; r2 < 4; r2++) {
                int row = tileM + wm * 64 + mi * 16 + sk * 4 + r2;
                float val = acc[mi][ni][r2] + bv;
                if (OUTF)
                    ((float*)Cout)[(size_t)row * 512 + col] = val;
                else
                    ((u16*)Cout)[(size_t)row * 512 + col] = f2b(val);
            }
        }
    }
}

__global__ __launch_bounds__(256) void proj3(
    const u16* __restrict__ xq, const u16* __restrict__ xk,
    const u16* __restrict__ xv, const u16* __restrict__ wtq,
    const u16* __restrict__ wtk, const u16* __restrict__ wtv,
    const float* __restrict__ bq, const float* __restrict__ bk,
    const float* __restrict__ bv, u16* __restrict__ Q, u16* __restrict__ K,
    u16* __restrict__ V) {
    int z = blockIdx.z;
    const u16* A = z == 0 ? xq : (z == 1 ? xk : xv);
    const u16* Bt = z == 0 ? wtq : (z == 1 ? wtk : wtv);
    const float* bias = z == 0 ? bq : (z == 1 ? bk : bv);
    u16* C = z == 0 ? Q : (z == 1 ? K : V);
    gemm128_body<0>(A, Bt, bias, C);
}

__global__ __launch_bounds__(256) void out_gemm(const u16* __restrict__ T,
                                                const u16* __restrict__ wto,
                                                const float* __restrict__ bo,
                                                float* __restrict__ C) {
    gemm128_body<1>(T, wto, bo, C);
}

// ---------- 4. rank-1 channel attention + residual-diff ----------
// per (n,h): x_att[i] = sum_j exp(q_i*k_j/8) v_j / sum_j exp(q_i*k_j/8)
__global__ __launch_bounds__(256) void attn_kernel(
    const u16* __restrict__ Qb, const u16* __restrict__ Kb,
    const u16* __restrict__ Vb, const float* __restrict__ xq,
    u16* __restrict__ Tout) {
    __shared__ float lk[4][64];
    __shared__ float lv[4][64];
    const int wave = threadIdx.x >> 6, lane = threadIdx.x & 63;
    const int p = blockIdx.x * 4 + wave;  // (n,h) pair, < 32768
    const int n = p >> 3, h = p & 7;
    const size_t base = (size_t)n * DMODEL + h * DKH;

    float q = b2f(Qb[base + lane]);
    lk[wave][lane] = b2f(Kb[base + lane]) * 0.125f;  // 1/sqrt(64)
    lv[wave][lane] = b2f(Vb[base + lane]);
    __syncthreads();

    float num = 0.f, den = 0.f;
#pragma unroll
    for (int j = 0; j < 64; j += 4) {
        float4 kv = *(const float4*)&lk[wave][j];
        float4 vv = *(const float4*)&lv[wave][j];
        float e0 = __expf(q * kv.x);
        float e1 = __expf(q * kv.y);
        float e2 = __expf(q * kv.z);
        float e3 = __expf(q * kv.w);
        den += e0 + e1 + e2 + e3;
        num += e0 * vv.x + e1 * vv.y + e2 * vv.z + e3 * vv.w;
    }
    float t = xq[base + lane] - num / den;
    Tout[base + lane] = f2b(t);
}

// ---------- launch ----------
extern "C" void kernel_launch(void* const* d_in, const int* in_sizes, int n_in,
                              void* d_out, int out_size, void* d_ws,
                              size_t ws_size, hipStream_t stream) {
    const float* x_q = (const float*)d_in[0];
    const float* x_k = (const float*)d_in[1];
    const float* x_v = (const float*)d_in[2];
    const float* Wq = (const float*)d_in[3];
    const float* bq = (const float*)d_in[4];
    const float* Wk = (const float*)d_in[5];
    const float* bk = (const float*)d_in[6];
    const float* Wv = (const float*)d_in[7];
    const float* bv = (const float*)d_in[8];
    const float* Wo = (const float*)d_in[9];
    const float* bo = (const float*)d_in[10];

    u16* ws = (u16*)d_ws;
    u16* xqb = ws;
    u16* xkb = xqb + ND;
    u16* xvb = xkb + ND;
    u16* wtq = xvb + ND;
    u16* wtk = wtq + DD;
    u16* wtv = wtk + DD;
    u16* wto = wtv + DD;
    u16* Qb = wto + DD;
    u16* Kb = Qb + ND;
    u16* Vb = Kb + ND;
    u16* Tb = Vb + ND;

    convert_x<<<dim3(ND / 4 / 256, 1, 3), 256, 0, stream>>>(x_q, x_k, x_v, xqb,
                                                            xkb, xvb, ND);
    convert_w<<<dim3(16, 16, 4), dim3(32, 8), 0, stream>>>(Wq, Wk, Wv, Wo, wtq,
                                                           wtk, wtv, wto);
    proj3<<<dim3(DMODEL / 128, NROWS / 128, 3), 256, 0, stream>>>(
        xqb, xkb, xvb, wtq, wtk, wtv, bq, bk, bv, Qb, Kb, Vb);
    attn_kernel<<<dim3(NROWS * NHEAD / 4), 256, 0, stream>>>(Qb, Kb, Vb, x_q,
                                                             Tb);
    out_gemm<<<dim3(DMODEL / 128, NROWS / 128), 256, 0, stream>>>(
        Tb, wto, bo, (float*)d_out);
}

// Round 3
// 136.510 us; speedup vs baseline: 1.0636x; 1.0519x over previous
//
#include <hip/hip_runtime.h>
#include <hip/hip_bf16.h>

#define NROWS 4096
#define DMODEL 512
#define NHEAD 8
#define DKH 64
#define ND (NROWS * DMODEL)   // 2097152
#define DD (DMODEL * DMODEL)  // 262144

typedef unsigned short u16;
typedef __attribute__((ext_vector_type(8))) short short8;
typedef __attribute__((ext_vector_type(4))) float floatx4;

// ---------- helpers ----------
__device__ __forceinline__ u16 f2b(float f) {
    unsigned u = __float_as_uint(f);
    unsigned r = (u + 0x7fffu + ((u >> 16) & 1u)) >> 16;
    return (u16)r;
}
__device__ __forceinline__ float b2f(u16 v) {
    return __uint_as_float(((unsigned)v) << 16);
}
__device__ __forceinline__ void async16(const void* g, void* l) {
    // global -> LDS direct, 16B/lane; LDS dest = wave-uniform base + lane*16
    __builtin_amdgcn_global_load_lds(g, l, 16, 0, 0);
}

// ---------- 1. W (K x N) -> Wt (N x K) bf16 ----------
__global__ __launch_bounds__(256) void convert_w(
    const float* __restrict__ W0, const float* __restrict__ W1,
    const float* __restrict__ W2, const float* __restrict__ W3,
    u16* __restrict__ T0, u16* __restrict__ T1, u16* __restrict__ T2,
    u16* __restrict__ T3) {
    __shared__ float tile[32][33];
    int z = blockIdx.z;
    const float* W = z == 0 ? W0 : (z == 1 ? W1 : (z == 2 ? W2 : W3));
    u16* T = z == 0 ? T0 : (z == 1 ? T1 : (z == 2 ? T2 : T3));
    int n0 = blockIdx.x * 32, k0 = blockIdx.y * 32;
    int tx = threadIdx.x, ty = threadIdx.y;  // (32, 8)
#pragma unroll
    for (int r = 0; r < 32; r += 8)
        tile[ty + r][tx] = W[(size_t)(k0 + ty + r) * DMODEL + n0 + tx];
    __syncthreads();
#pragma unroll
    for (int r = 0; r < 32; r += 8) {
        int n = n0 + ty + r, k = k0 + tx;
        T[(size_t)n * DMODEL + k] = f2b(tile[tx][ty + r]);
    }
}

// ---------- 2. fused convert + projection GEMM ----------
// C[4096,512] = bf16(xf32)[M,K] @ Wt[N,K]^T + bias, per z in {Q,K,V}.
// BM=64, BN=128, BK=32. 256 thr = 4 waves (wm 2 x wn 2), per-wave 32x64,
// acc[2][4]. Double-buffered LDS, 1 barrier per K-step (T3-minimum).
__global__ __launch_bounds__(256) void proj3(
    const float* __restrict__ xq, const float* __restrict__ xk,
    const float* __restrict__ xv, const u16* __restrict__ wtq,
    const u16* __restrict__ wtk, const u16* __restrict__ wtv,
    const float* __restrict__ bq, const float* __restrict__ bk,
    const float* __restrict__ bv, u16* __restrict__ Q, u16* __restrict__ K,
    u16* __restrict__ V) {
    // XCD-chunked remap: 768 blocks, 8 XCDs, 96 consecutive tiles per XCD
    int d = blockIdx.x;
    int id = (d & 7) * 96 + (d >> 3);
    int z = id >> 8;        // 256 tiles per z
    int t2 = id & 255;      // within z: 64 M-panels x 4 N-tiles
    const int tileM = (t2 >> 2) * 64;
    const int tileN = (t2 & 3) * 128;

    const float* A = z == 0 ? xq : (z == 1 ? xk : xv);
    const u16* Bt = z == 0 ? wtq : (z == 1 ? wtk : wtv);
    const float* bias = z == 0 ? bq : (z == 1 ? bk : bv);
    u16* C = z == 0 ? Q : (z == 1 ? K : V);

    __shared__ __align__(16) u16 lA[2][64 * 32];
    __shared__ __align__(16) u16 lB[2][128 * 32];

    const int tid = threadIdx.x;
    const int wave = tid >> 6, lane = tid & 63;
    const int wm = wave >> 1, wn = wave & 1;
    const int lr4 = lane >> 2, ls = lane & 3;
    const int lrow = lane & 15, sk = lane >> 4;

    // A reg-staging geometry: thread -> (row, 8-elem slot)
    const int ar = tid >> 2;   // 0..63
    const int asl = tid & 3;   // k-slot
    const int asw = asl ^ ((ar >> 1) & 3);          // swizzled LDS slot
    const float* aptr = A + (size_t)(tileM + ar) * 512 + asl * 8;
    u16* const awr0 = &lA[0][ar * 32 + asw * 8];
    u16* const awr1 = &lA[1][ar * 32 + asw * 8];

    // B async16 staging geometry (2 chunks of 16 rows per wave)
    int br0 = (wave * 2) * 16 + lr4;
    int br1 = (wave * 2 + 1) * 16 + lr4;
    int bs0 = ls ^ ((br0 >> 1) & 3);
    int bs1 = ls ^ ((br1 >> 1) & 3);
    const u16* bptr0 = Bt + (size_t)(tileN + br0) * 512 + bs0 * 8;
    const u16* bptr1 = Bt + (size_t)(tileN + br1) * 512 + bs1 * 8;
    u16* const bwr0_0 = &lB[0][(wave * 2) * 512];
    u16* const bwr0_1 = &lB[0][(wave * 2 + 1) * 512];
    u16* const bwr1_0 = &lB[1][(wave * 2) * 512];
    u16* const bwr1_1 = &lB[1][(wave * 2 + 1) * 512];

    floatx4 acc[2][4];
#pragma unroll
    for (int i = 0; i < 2; i++)
#pragma unroll
        for (int j = 0; j < 4; j++) acc[i][j] = (floatx4){0.f, 0.f, 0.f, 0.f};

    // ---- prologue: stage tile 0 into buffer 0
    async16(bptr0, bwr0_0);
    async16(bptr1, bwr0_1);
    {
        float4 a0 = *(const float4*)aptr;
        float4 a1 = *(const float4*)(aptr + 4);
        short8 av;
        av[0] = f2b(a0.x); av[1] = f2b(a0.y); av[2] = f2b(a0.z); av[3] = f2b(a0.w);
        av[4] = f2b(a1.x); av[5] = f2b(a1.y); av[6] = f2b(a1.z); av[7] = f2b(a1.w);
        *(short8*)awr0 = av;
    }
    __syncthreads();

    for (int t = 0; t < 16; ++t) {
        const int cur = t & 1;
        float4 na0, na1;
        if (t < 15) {
            // issue next-tile loads first: A to regs, B direct to alt buffer
            const float* p = aptr + (t + 1) * 32;
            na0 = *(const float4*)p;
            na1 = *(const float4*)(p + 4);
            const u16* q0 = bptr0 + (t + 1) * 32;
            const u16* q1 = bptr1 + (t + 1) * 32;
            if (cur == 0) {
                async16(q0, bwr1_0);
                async16(q1, bwr1_1);
            } else {
                async16(q0, bwr0_0);
                async16(q1, bwr0_1);
            }
        }
        // compute current tile
        short8 bfr[4], afr[2];
#pragma unroll
        for (int ni = 0; ni < 4; ++ni) {
            int r = wn * 64 + ni * 16 + lrow;
            int s = sk ^ ((r >> 1) & 3);
            bfr[ni] = *(const short8*)&lB[cur][r * 32 + s * 8];
        }
#pragma unroll
        for (int mi = 0; mi < 2; ++mi) {
            int r = wm * 32 + mi * 16 + lrow;
            int s = sk ^ ((r >> 1) & 3);
            afr[mi] = *(const short8*)&lA[cur][r * 32 + s * 8];
        }
#pragma unroll
        for (int mi = 0; mi < 2; ++mi)
#pragma unroll
            for (int ni = 0; ni < 4; ++ni)
                acc[mi][ni] = __builtin_amdgcn_mfma_f32_16x16x32_bf16(
                    afr[mi], bfr[ni], acc[mi][ni], 0, 0, 0);
        if (t < 15) {
            short8 av;
            av[0] = f2b(na0.x); av[1] = f2b(na0.y); av[2] = f2b(na0.z); av[3] = f2b(na0.w);
            av[4] = f2b(na1.x); av[5] = f2b(na1.y); av[6] = f2b(na1.z); av[7] = f2b(na1.w);
            *(short8*)(cur == 0 ? awr1 : awr0) = av;
        }
        __syncthreads();
    }

    // epilogue: C/D layout col = lane&15, row = (lane>>4)*4 + reg
#pragma unroll
    for (int mi = 0; mi < 2; ++mi) {
#pragma unroll
        for (int ni = 0; ni < 4; ++ni) {
            int col = tileN + wn * 64 + ni * 16 + lrow;
            float bv = bias[col];
#pragma unroll
            for (int r2 = 0; r2 < 4; r2++) {
                int row = tileM + wm * 32 + mi * 16 + sk * 4 + r2;
                C[(size_t)row * 512 + col] = f2b(acc[mi][ni][r2] + bv);
            }
        }
    }
}

// ---------- 3. output GEMM: C = T[M,K] @ Wto[N,K]^T + bo (fp32 out) ----------
// Same geometry; A is bf16 via async16 (4 chunks of 16 rows, 1 per wave).
__global__ __launch_bounds__(256) void out_gemm(const u16* __restrict__ T,
                                                const u16* __restrict__ wto,
                                                const float* __restrict__ bo,
                                                float* __restrict__ C) {
    int d = blockIdx.x;                 // 256 blocks
    int id = (d & 7) * 32 + (d >> 3);   // chunked per XCD
    const int tileM = (id >> 2) * 64;
    const int tileN = (id & 3) * 128;

    __shared__ __align__(16) u16 lA[2][64 * 32];
    __shared__ __align__(16) u16 lB[2][128 * 32];

    const int tid = threadIdx.x;
    const int wave = tid >> 6, lane = tid & 63;
    const int wm = wave >> 1, wn = wave & 1;
    const int lr4 = lane >> 2, ls = lane & 3;
    const int lrow = lane & 15, sk = lane >> 4;

    int ar = wave * 16 + lr4;
    int as = ls ^ ((ar >> 1) & 3);
    const u16* aptr = T + (size_t)(tileM + ar) * 512 + as * 8;
    u16* const awr0 = &lA[0][wave * 512];
    u16* const awr1 = &lA[1][wave * 512];

    int br0 = (wave * 2) * 16 + lr4;
    int br1 = (wave * 2 + 1) * 16 + lr4;
    int bs0 = ls ^ ((br0 >> 1) & 3);
    int bs1 = ls ^ ((br1 >> 1) & 3);
    const u16* bptr0 = wto + (size_t)(tileN + br0) * 512 + bs0 * 8;
    const u16* bptr1 = wto + (size_t)(tileN + br1) * 512 + bs1 * 8;
    u16* const bwr0_0 = &lB[0][(wave * 2) * 512];
    u16* const bwr0_1 = &lB[0][(wave * 2 + 1) * 512];
    u16* const bwr1_0 = &lB[1][(wave * 2) * 512];
    u16* const bwr1_1 = &lB[1][(wave * 2 + 1) * 512];

    floatx4 acc[2][4];
#pragma unroll
    for (int i = 0; i < 2; i++)
#pragma unroll
        for (int j = 0; j < 4; j++) acc[i][j] = (floatx4){0.f, 0.f, 0.f, 0.f};

    async16(aptr, awr0);
    async16(bptr0, bwr0_0);
    async16(bptr1, bwr0_1);
    __syncthreads();

    for (int t = 0; t < 16; ++t) {
        const int cur = t & 1;
        if (t < 15) {
            const u16* pa = aptr + (t + 1) * 32;
            const u16* q0 = bptr0 + (t + 1) * 32;
            const u16* q1 = bptr1 + (t + 1) * 32;
            if (cur == 0) {
                async16(pa, awr1);
                async16(q0, bwr1_0);
                async16(q1, bwr1_1);
            } else {
                async16(pa, awr0);
                async16(q0, bwr0_0);
                async16(q1, bwr0_1);
            }
        }
        short8 bfr[4], afr[2];
#pragma unroll
        for (int ni = 0; ni < 4; ++ni) {
            int r = wn * 64 + ni * 16 + lrow;
            int s = sk ^ ((r >> 1) & 3);
            bfr[ni] = *(const short8*)&lB[cur][r * 32 + s * 8];
        }
#pragma unroll
        for (int mi = 0; mi < 2; ++mi) {
            int r = wm * 32 + mi * 16 + lrow;
            int s = sk ^ ((r >> 1) & 3);
            afr[mi] = *(const short8*)&lA[cur][r * 32 + s * 8];
        }
#pragma unroll
        for (int mi = 0; mi < 2; ++mi)
#pragma unroll
            for (int ni = 0; ni < 4; ++ni)
                acc[mi][ni] = __builtin_amdgcn_mfma_f32_16x16x32_bf16(
                    afr[mi], bfr[ni], acc[mi][ni], 0, 0, 0);
        __syncthreads();
    }

#pragma unroll
    for (int mi = 0; mi < 2; ++mi) {
#pragma unroll
        for (int ni = 0; ni < 4; ++ni) {
            int col = tileN + wn * 64 + ni * 16 + lrow;
            float bv = bo[col];
#pragma unroll
            for (int r2 = 0; r2 < 4; r2++) {
                int row = tileM + wm * 32 + mi * 16 + sk * 4 + r2;
                C[(size_t)row * 512 + col] = acc[mi][ni][r2] + bv;
            }
        }
    }
}

// ---------- 4. rank-1 channel attention + residual-diff ----------
__global__ __launch_bounds__(256) void attn_kernel(
    const u16* __restrict__ Qb, const u16* __restrict__ Kb,
    const u16* __restrict__ Vb, const float* __restrict__ xq,
    u16* __restrict__ Tout) {
    __shared__ float lk[4][64];
    __shared__ float lv[4][64];
    const int wave = threadIdx.x >> 6, lane = threadIdx.x & 63;
    const int p = blockIdx.x * 4 + wave;  // (n,h) pair, < 32768
    const int n = p >> 3, h = p & 7;
    const size_t base = (size_t)n * DMODEL + h * DKH;

    float q = b2f(Qb[base + lane]);
    lk[wave][lane] = b2f(Kb[base + lane]) * 0.125f;  // 1/sqrt(64)
    lv[wave][lane] = b2f(Vb[base + lane]);
    __syncthreads();

    float num = 0.f, den = 0.f;
#pragma unroll
    for (int j = 0; j < 64; j += 4) {
        float4 kv = *(const float4*)&lk[wave][j];
        float4 vv = *(const float4*)&lv[wave][j];
        float e0 = __expf(q * kv.x);
        float e1 = __expf(q * kv.y);
        float e2 = __expf(q * kv.z);
        float e3 = __expf(q * kv.w);
        den += e0 + e1 + e2 + e3;
        num += e0 * vv.x + e1 * vv.y + e2 * vv.z + e3 * vv.w;
    }
    float t = xq[base + lane] - num / den;
    Tout[base + lane] = f2b(t);
}

// ---------- launch ----------
extern "C" void kernel_launch(void* const* d_in, const int* in_sizes, int n_in,
                              void* d_out, int out_size, void* d_ws,
                              size_t ws_size, hipStream_t stream) {
    const float* x_q = (const float*)d_in[0];
    const float* x_k = (const float*)d_in[1];
    const float* x_v = (const float*)d_in[2];
    const float* Wq = (const float*)d_in[3];
    const float* bq = (const float*)d_in[4];
    const float* Wk = (const float*)d_in[5];
    const float* bk = (const float*)d_in[6];
    const float* Wv = (const float*)d_in[7];
    const float* bv = (const float*)d_in[8];
    const float* Wo = (const float*)d_in[9];
    const float* bo = (const float*)d_in[10];

    u16* ws = (u16*)d_ws;
    u16* wtq = ws;
    u16* wtk = wtq + DD;
    u16* wtv = wtk + DD;
    u16* wto = wtv + DD;
    u16* Qb = wto + DD;
    u16* Kb = Qb + ND;
    u16* Vb = Kb + ND;
    u16* Tb = Vb + ND;

    convert_w<<<dim3(16, 16, 4), dim3(32, 8), 0, stream>>>(Wq, Wk, Wv, Wo, wtq,
                                                           wtk, wtv, wto);
    proj3<<<dim3(768), 256, 0, stream>>>(x_q, x_k, x_v, wtq, wtk, wtv, bq, bk,
                                         bv, Qb, Kb, Vb);
    attn_kernel<<<dim3(NROWS * NHEAD / 4), 256, 0, stream>>>(Qb, Kb, Vb, x_q,
                                                             Tb);
    out_gemm<<<dim3(256), 256, 0, stream>>>(Tb, wto, bo, (float*)d_out);
}